// Round 2
// baseline (37735.135 us; speedup 1.0000x reference)
//
#include <hip/hip_runtime.h>

#define THREADS 256
#define T_TOT 432
#define T_IN  144
#define T_OUT 288

// ws layout (floats):
// [0,65536) h1 buf0   [65536,131072) h1 buf1    (transposed: [b=256][k=256])
// [131072,196608) h2 buf0   [196608,262144) h2 buf1
// [262144, +512 u32) split barrier counters: 8 groups x (cntA @ +g*64, cntB @ +g*64+32)

__device__ __forceinline__ float sigf(float x){ return 1.0f/(1.0f + __expf(-x)); }
__device__ __forceinline__ float tanhfast(float x){ return 1.0f - 2.0f/(__expf(2.0f*x)+1.0f); }

extern "C" __global__ void gru_init(float* __restrict__ ws, float* __restrict__ out,
                                    const float* __restrict__ b_proj){
  int i = blockIdx.x*THREADS + threadIdx.x;
  if (i < 262144) ws[i] = 0.0f;
  if (i < 512) ((unsigned*)(ws + 262144))[i] = 0u;
  if (i < 73728) out[i] = b_proj[0];
}

// LDS float4 offsets
#define WSTRIDE 1552            // per-mat W stride (float4), max addr 1547
#define HA_OFF  4656            // 3*1552
#define HB_OFF  6720            // HA_OFF + 2064
#define PRJ_OFF 35136           // (6720+2064)*4  (float index)
#define LDS_BYTES 141568        // (35136+256)*4

extern "C" __global__ void __launch_bounds__(THREADS, 1) gru_persist(
    const float* __restrict__ x,
    const float* __restrict__ wih0, const float* __restrict__ whh0,
    const float* __restrict__ bih0, const float* __restrict__ bhh0,
    const float* __restrict__ wih1, const float* __restrict__ whh1,
    const float* __restrict__ bih1, const float* __restrict__ bhh1,
    const float* __restrict__ wproj,
    float* __restrict__ out, float* __restrict__ ws)
{
  extern __shared__ float lds[];
  float4* WL4 = (float4*)lds;
  float4* HA4 = WL4 + HA_OFF;
  float4* HB4 = WL4 + HB_OFF;
  const float* HAf = (const float*)HA4;
  const float* HBf = (const float*)HB4;
  float* PRJ = lds + PRJ_OFF;

  const int tid = threadIdx.x;
  const int g   = blockIdx.x & 31;    // hidden slice (8 rows)
  const int bt  = blockIdx.x >> 5;    // batch tile (32 cols)
  const int hi  = tid >> 5;           // 0..7
  const int bg  = (tid >> 2) & 7;     // 0..7
  const int ks  = tid & 3;            // K quarter
  const int bco = (bg << 2) | ks;     // owned batch col 0..31
  const int rowg = g*8 + hi;          // global hidden row
  const int btb  = bt << 5;           // batch base

  float* h1b0 = ws;
  float* h1b1 = ws + 65536;
  float* h2b0 = ws + 131072;
  float* h2b1 = ws + 196608;
  unsigned* cntA = ((unsigned*)(ws + 262144)) + (bt << 6);
  unsigned* cntB = cntA + 32;

  // ---- one-time: weight slices into skewed LDS [k4*24 + row + 4*(k4>>4)] ----
  {
    const float* srcs[3] = {whh0, wih1, whh1};
    #pragma unroll
    for (int m = 0; m < 3; m++){
      const float* S = srcs[m];
      for (int i = 0; i < 6; i++){
        int idx = tid + (i << 8);        // 0..1535
        int row = idx % 24;              // gate*8 + hh
        int k4  = idx / 24;              // 0..63
        int gate = row >> 3, hh = row & 7;
        float4 v = *(const float4*)(S + (gate*256 + g*8 + hh)*256 + (k4 << 2));
        WL4[m*WSTRIDE + k4*24 + row + ((k4 >> 4) << 2)] = v;
      }
    }
  }
  // ---- per-thread small weights ----
  float wi0[3][10];
  float bi0g[3], bh0g[3], bi1g[3], bh1g[3];
  #pragma unroll
  for (int G = 0; G < 3; G++){
    #pragma unroll
    for (int d = 0; d < 10; d++) wi0[G][d] = wih0[(G*256 + rowg)*10 + d];
    bi0g[G] = bih0[G*256 + rowg];
    bh0g[G] = bhh0[G*256 + rowg];
    bi1g[G] = bih1[G*256 + rowg];
    bh1g[G] = bhh1[G*256 + rowg];
  }
  const float wp = wproj[rowg];

  // stage transposed-global h tile [32 bcol][256 k] -> skewed LDS
  auto STAGE = [&](const float* __restrict__ hg, float4* __restrict__ H4){
    #pragma unroll
    for (int i = 0; i < 8; i++){
      int idx = tid + (i << 8);          // 0..2047
      int k4 = idx & 63;
      int bc = idx >> 6;                 // 0..31
      float4 v = *(const float4*)(hg + (btb + bc)*256 + (k4 << 2));
      H4[(k4 << 5) + bc + (k4 >> 4)] = v;
    }
  };

  auto GEMM3 = [&](const float4* __restrict__ H4, int m,
                   float (&aR)[4], float (&aZ)[4], float (&aN)[4]){
    const float4* Wm = WL4 + m*WSTRIDE;
    const int wo = ks*388 + hi;          // ks*384 + 4*ks + hi
    const int ho = ks*513 + (bg << 2);   // ks*512 + ks + bg*4
    #pragma unroll 4
    for (int j = 0; j < 16; j++){
      float4 wr = Wm[wo + j*24];
      float4 wz = Wm[wo + 8 + j*24];
      float4 wn = Wm[wo + 16 + j*24];
      #pragma unroll
      for (int bb = 0; bb < 4; bb++){
        float4 hv = H4[ho + (j << 5) + bb];
        aR[bb] = fmaf(wr.x,hv.x, fmaf(wr.y,hv.y, fmaf(wr.z,hv.z, fmaf(wr.w,hv.w, aR[bb]))));
        aZ[bb] = fmaf(wz.x,hv.x, fmaf(wz.y,hv.y, fmaf(wz.z,hv.z, fmaf(wz.w,hv.w, aZ[bb]))));
        aN[bb] = fmaf(wn.x,hv.x, fmaf(wn.y,hv.y, fmaf(wn.z,hv.z, fmaf(wn.w,hv.w, aN[bb]))));
      }
    }
  };

  auto KRED = [&](float v){
    v += __shfl_xor(v, 1, 64);
    v += __shfl_xor(v, 2, 64);
    return v;
  };
  auto SEL4 = [&](float a0, float a1, float a2, float a3){
    return ks == 0 ? a0 : (ks == 1 ? a1 : (ks == 2 ? a2 : a3));
  };
  auto ldH = [&](const float* Hf, int row, int bc){
    int k4 = row >> 2;
    return Hf[(((k4 << 5) + bc + (k4 >> 4)) << 2) + (row & 3)];
  };
  auto WAIT = [&](unsigned* c, unsigned tgt){
    while (__hip_atomic_load(c, __ATOMIC_ACQUIRE, __HIP_MEMORY_SCOPE_AGENT) < tgt)
      __builtin_amdgcn_s_sleep(1);
  };

  __syncthreads();
  STAGE(h1b0, HA4);                     // h1[-1] = 0 tile
  __syncthreads();

  int p = 0;
  for (int t = 0; t < T_TOT; t++){
    const float* h2prev = p ? h2b1 : h2b0;
    float* h1nxt = p ? h1b0 : h1b1;
    float* h2nxt = p ? h2b0 : h2b1;

    // ---------------- layer 0: whh0 . h1[t-1] (HA resident) ----------------
    float aR[4] = {0,0,0,0}, aZ[4] = {0,0,0,0}, aN[4] = {0,0,0,0};
    GEMM3(HA4, 0, aR, aZ, aN);
    float hr = SEL4(KRED(aR[0]),KRED(aR[1]),KRED(aR[2]),KRED(aR[3])) + bh0g[0];
    float hz = SEL4(KRED(aZ[0]),KRED(aZ[1]),KRED(aZ[2]),KRED(aZ[3])) + bh0g[1];
    float hn = SEL4(KRED(aN[0]),KRED(aN[1]),KRED(aN[2]),KRED(aN[3])) + bh0g[2];
    float xr = bi0g[0], xz = bi0g[1], xn = bi0g[2];
    if (t < T_IN){
      const float* xp = x + (btb + bco)*(T_IN*10) + t*10;
      #pragma unroll
      for (int d = 0; d < 10; d++){
        float xv = xp[d];
        xr = fmaf(wi0[0][d], xv, xr);
        xz = fmaf(wi0[1][d], xv, xz);
        xn = fmaf(wi0[2][d], xv, xn);
      }
    }
    float r = sigf(xr + hr);
    float z = sigf(xz + hz);
    float n = tanhfast(xn + r*hn);
    float hold = ldH(HAf, rowg, bco);
    float hnew1 = fmaf(z, hold - n, n);
    h1nxt[(btb + bco)*256 + rowg] = hnew1;
    __threadfence();
    __syncthreads();                                           // bar1
    if (tid == 0)
      __hip_atomic_fetch_add(cntA, 1u, __ATOMIC_RELEASE, __HIP_MEMORY_SCOPE_AGENT);

    // wait#0: all h2[t-1] written (cntB >= 32t), overlapped with GEMM0 above
    WAIT(cntB, 32u*(unsigned)t);
    STAGE(h2prev, HB4);
    __syncthreads();                                           // bar2

    // ---------------- layer 1 part A: whh1 . h2[t-1] ----------------
    float bR[4] = {0,0,0,0}, bZ[4] = {0,0,0,0}, bN[4] = {0,0,0,0};
    GEMM3(HB4, 2, bR, bZ, bN);

    // wait#1: all h1[t] written (cntA >= 32(t+1)), overlapped with GEMM2
    WAIT(cntA, 32u*(unsigned)(t+1));
    STAGE(h1nxt, HA4);                  // h1[t] -> resident for GEMM1 + next GEMM0
    __syncthreads();                                           // bar3

    // ---------------- layer 1 part B: wih1 . h1[t] ----------------
    float xR[4] = {0,0,0,0}, xZ[4] = {0,0,0,0}, xN[4] = {0,0,0,0};
    GEMM3(HA4, 1, xR, xZ, xN);
    float xr1 = SEL4(KRED(xR[0]),KRED(xR[1]),KRED(xR[2]),KRED(xR[3])) + bi1g[0];
    float xz1 = SEL4(KRED(xZ[0]),KRED(xZ[1]),KRED(xZ[2]),KRED(xZ[3])) + bi1g[1];
    float xn1 = SEL4(KRED(xN[0]),KRED(xN[1]),KRED(xN[2]),KRED(xN[3])) + bi1g[2];
    float hr1 = SEL4(KRED(bR[0]),KRED(bR[1]),KRED(bR[2]),KRED(bR[3])) + bh1g[0];
    float hz1 = SEL4(KRED(bZ[0]),KRED(bZ[1]),KRED(bZ[2]),KRED(bZ[3])) + bh1g[1];
    float hn1 = SEL4(KRED(bN[0]),KRED(bN[1]),KRED(bN[2]),KRED(bN[3])) + bh1g[2];
    float r1 = sigf(xr1 + hr1);
    float z1 = sigf(xz1 + hz1);
    float n1 = tanhfast(xn1 + r1*hn1);
    float h2old = ldH(HBf, rowg, bco);
    float h2new = fmaf(z1, h2old - n1, n1);
    h2nxt[(btb + bco)*256 + rowg] = h2new;
    if (t >= T_IN) PRJ[tid] = h2new * wp;
    __threadfence();
    __syncthreads();                                           // bar4
    if (tid == 0)
      __hip_atomic_fetch_add(cntB, 1u, __ATOMIC_RELEASE, __HIP_MEMORY_SCOPE_AGENT);

    // projection finish: 8-row partial per bcol, one atomic per col
    if (t >= T_IN && tid < 32){
      float s = 0.0f;
      #pragma unroll
      for (int hh = 0; hh < 8; hh++) s += PRJ[hh*32 + tid];
      atomicAdd(out + (btb + tid)*T_OUT + (t - T_IN), s);
    }
    p ^= 1;
  }
}

extern "C" void kernel_launch(void* const* d_in, const int* in_sizes, int n_in,
                              void* d_out, int out_size, void* d_ws, size_t ws_size,
                              hipStream_t stream){
  const float* x     = (const float*)d_in[0];
  const float* wih0  = (const float*)d_in[1];
  const float* whh0  = (const float*)d_in[2];
  const float* bih0  = (const float*)d_in[3];
  const float* bhh0  = (const float*)d_in[4];
  const float* wih1  = (const float*)d_in[5];
  const float* whh1  = (const float*)d_in[6];
  const float* bih1  = (const float*)d_in[7];
  const float* bhh1  = (const float*)d_in[8];
  const float* wproj = (const float*)d_in[9];
  const float* bproj = (const float*)d_in[10];
  float* out = (float*)d_out;
  float* ws  = (float*)d_ws;

  hipLaunchKernelGGL(gru_init, dim3(1024), dim3(THREADS), 0, stream, ws, out, bproj);

  hipFuncSetAttribute(reinterpret_cast<const void*>(gru_persist),
                      hipFuncAttributeMaxDynamicSharedMemorySize, LDS_BYTES);

  void* args[] = {
    (void*)&x, (void*)&wih0, (void*)&whh0, (void*)&bih0, (void*)&bhh0,
    (void*)&wih1, (void*)&whh1, (void*)&bih1, (void*)&bhh1,
    (void*)&wproj, (void*)&out, (void*)&ws
  };
  hipLaunchCooperativeKernel(reinterpret_cast<void*>(gru_persist),
                             dim3(256), dim3(THREADS), args, LDS_BYTES, stream);
}

// Round 4
// 23599.570 us; speedup vs baseline: 1.5990x; 1.5990x over previous
//
#include <hip/hip_runtime.h>

#define THREADS 256
#define T_TOT 432
#define T_IN  144
#define T_OUT 288

// LDS float4 offsets
#define WSTRIDE 1552            // per-mat W stride (float4)
#define HA_OFF  4656            // 3*1552
#define HB_OFF  6704            // HA_OFF + 2048
#define PRJ_OFF 35008           // (HB_OFF+2048)*4 (float index)
#define LDS_BYTES 141056        // (PRJ_OFF+256)*4

// ws layout (floats): h1b0 [0,64K) h1b1 [64K,128K) h2b0 [128K,192K) h2b1 [192K,256K)
//   (global h layout: [k=256][b=256])
// counters: 512 uints at ws+262144; group bt: cntA = +bt*64, cntB = +bt*64+32

#define FMA4(a,h,s) { a.x=fmaf((h).x,(s),a.x); a.y=fmaf((h).y,(s),a.y); \
                      a.z=fmaf((h).z,(s),a.z); a.w=fmaf((h).w,(s),a.w); }

__device__ __forceinline__ float sigf(float x){ return 1.0f/(1.0f + __expf(-x)); }
__device__ __forceinline__ float tanhfast(float x){ return 1.0f - 2.0f/(__expf(2.0f*x)+1.0f); }

template<int CTRL>
__device__ __forceinline__ float4 dpp_add(float4 v){
  float4 r;
  r.x = v.x + __int_as_float(__builtin_amdgcn_update_dpp(0, __float_as_int(v.x), CTRL, 0xf, 0xf, true));
  r.y = v.y + __int_as_float(__builtin_amdgcn_update_dpp(0, __float_as_int(v.y), CTRL, 0xf, 0xf, true));
  r.z = v.z + __int_as_float(__builtin_amdgcn_update_dpp(0, __float_as_int(v.z), CTRL, 0xf, 0xf, true));
  r.w = v.w + __int_as_float(__builtin_amdgcn_update_dpp(0, __float_as_int(v.w), CTRL, 0xf, 0xf, true));
  return r;
}
__device__ __forceinline__ float4 kred4(float4 v){
  v = dpp_add<177>(v);   // quad_perm [1,0,3,2]  (xor 1)
  v = dpp_add<78>(v);    // quad_perm [2,3,0,1]  (xor 2)
  return v;
}

extern "C" __global__ void gru_init(float* __restrict__ ws, float* __restrict__ out,
                                    const float* __restrict__ b_proj){
  int i = blockIdx.x*THREADS + threadIdx.x;
  if (i < 262144) ws[i] = 0.0f;
  if (i < 512) ((unsigned*)(ws + 262144))[i] = 0u;
  if (i < 73728) out[i] = b_proj[0];
}

extern "C" __global__ void __launch_bounds__(THREADS, 1) gru_persist(
    const float* __restrict__ x,
    const float* __restrict__ wih0, const float* __restrict__ whh0,
    const float* __restrict__ bih0, const float* __restrict__ bhh0,
    const float* __restrict__ wih1, const float* __restrict__ whh1,
    const float* __restrict__ bih1, const float* __restrict__ bhh1,
    const float* __restrict__ wproj,
    float* __restrict__ out, float* __restrict__ ws)
{
  extern __shared__ float lds[];
  float4* WL4 = (float4*)lds;
  float4* HA4 = WL4 + HA_OFF;
  float4* HB4 = WL4 + HB_OFF;
  const float* HAf = (const float*)HA4;
  const float* HBf = (const float*)HB4;
  float* PRJ = lds + PRJ_OFF;

  const int tid = threadIdx.x;
  const int bt  = blockIdx.x & 7;     // batch tile — XCD-local group (round-robin dispatch)
  const int g   = blockIdx.x >> 3;    // hidden slice (8 rows)
  const int hi  = tid >> 5;           // 0..7
  const int bg  = (tid >> 2) & 7;     // 0..7 (4-batch group)
  const int ks  = tid & 3;            // K quarter
  const int bco = (bg << 2) | ks;     // owned batch col 0..31
  const int rowg = g*8 + hi;
  const int btb  = bt << 5;

  float* h1b0 = ws;
  float* h1b1 = ws + 65536;
  float* h2b0 = ws + 131072;
  float* h2b1 = ws + 196608;
  unsigned* cntA = ((unsigned*)(ws + 262144)) + (bt << 6);
  unsigned* cntB = cntA + 32;

  // ---- one-time: W slices -> skewed LDS [k4*24 + row + 4*(k4>>4)] (2-way reads = free) ----
  {
    const float* srcs[3] = {whh0, wih1, whh1};
    #pragma unroll
    for (int m = 0; m < 3; m++){
      const float* S = srcs[m];
      for (int i = 0; i < 6; i++){
        int idx = tid + (i << 8);
        int row = idx % 24;
        int k4  = idx / 24;
        int gate = row >> 3, hh = row & 7;
        float4 v = *(const float4*)(S + (gate*256 + g*8 + hh)*256 + (k4 << 2));
        WL4[m*WSTRIDE + k4*24 + row + ((k4 >> 4) << 2)] = v;
      }
    }
  }
  float wi0[3][10];
  float bi0g[3], bh0g[3], bi1g[3], bh1g[3];
  #pragma unroll
  for (int G = 0; G < 3; G++){
    #pragma unroll
    for (int d = 0; d < 10; d++) wi0[G][d] = wih0[(G*256 + rowg)*10 + d];
    bi0g[G] = bih0[G*256 + rowg];
    bh0g[G] = bhh0[G*256 + rowg];
    bi1g[G] = bih1[G*256 + rowg];
    bh1g[G] = bhh1[G*256 + rowg];
  }
  const float wp = wproj[rowg];
  // owner-readback index into H tile (conflict-free scalar)
  const int hIdx = (rowg << 5) + ((((bco >> 2) + ((rowg >> 6) << 1)) & 7) << 2) + (bco & 3);

  // H tile LDS layout: addr4(k,bq) = 8k + ((bq + 2*(k>>6)) & 7); conflict-free read+write
  float4 hreg[8];
  auto SLOAD = [&](const float* __restrict__ hg){
    #pragma unroll
    for (int i = 0; i < 8; i++){
      int idx = tid + (i << 8);
      hreg[i] = *(const float4*)(hg + ((idx >> 3) << 8) + btb + ((idx & 7) << 2));
    }
  };
  auto SWRITE = [&](float4* __restrict__ H4){
    #pragma unroll
    for (int i = 0; i < 8; i++){
      int idx = tid + (i << 8);
      int k = idx >> 3, bq = idx & 7;
      H4[(k << 3) + ((bq + ((k >> 6) << 1)) & 7)] = hreg[i];
    }
  };

  auto GEMM3 = [&](const float4* __restrict__ H4, int m,
                   float4& aR, float4& aZ, float4& aN){
    const float4* Wm = WL4 + m*WSTRIDE;
    const int wo = ks*388 + hi;
    const int hb = (ks << 9) + ((bg + (ks << 1)) & 7);
    #pragma unroll 4
    for (int j = 0; j < 16; j++){
      float4 wr = Wm[wo + j*24];
      float4 wz = Wm[wo + 8 + j*24];
      float4 wn = Wm[wo + 16 + j*24];
      float4 h0 = H4[hb + (j << 5)];
      float4 h1v = H4[hb + (j << 5) + 8];
      float4 h2v = H4[hb + (j << 5) + 16];
      float4 h3v = H4[hb + (j << 5) + 24];
      FMA4(aR,h0,wr.x) FMA4(aR,h1v,wr.y) FMA4(aR,h2v,wr.z) FMA4(aR,h3v,wr.w)
      FMA4(aZ,h0,wz.x) FMA4(aZ,h1v,wz.y) FMA4(aZ,h2v,wz.z) FMA4(aZ,h3v,wz.w)
      FMA4(aN,h0,wn.x) FMA4(aN,h1v,wn.y) FMA4(aN,h2v,wn.z) FMA4(aN,h3v,wn.w)
    }
  };

  auto SEL4 = [&](float4 v){
    return ks == 0 ? v.x : (ks == 1 ? v.y : (ks == 2 ? v.z : v.w));
  };
  auto WAIT = [&](unsigned* c, unsigned tgt){
    while (__hip_atomic_load(c, __ATOMIC_ACQUIRE, __HIP_MEMORY_SCOPE_AGENT) < tgt)
      __builtin_amdgcn_s_sleep(1);
  };

  __syncthreads();
  SLOAD(h1b1); SWRITE(HA4);            // h1[-1] = 0 tile (h1b1 zeroed)
  __syncthreads();

  for (int t = 0; t < T_TOT; t++){
    const float* h2prev = (t & 1) ? h2b0 : h2b1;
    float* h1nxt = (t & 1) ? h1b1 : h1b0;
    float* h2nxt = (t & 1) ? h2b1 : h2b0;

    // wait: h2[t-1] published (arriveB(t-1)); almost always instant
    if (tid == 0) WAIT(cntB, 32u*(unsigned)t);
    __syncthreads();                                          // bar1
    SLOAD(h2prev);                     // issue early; lands under GEMM0

    // ---------------- layer 0: whh0 . h1[t-1] (HA resident) ----------------
    float4 aR = {0,0,0,0}, aZ = {0,0,0,0}, aN = {0,0,0,0};
    GEMM3(HA4, 0, aR, aZ, aN);
    aR = kred4(aR); aZ = kred4(aZ); aN = kred4(aN);
    float hr = SEL4(aR) + bh0g[0];
    float hz = SEL4(aZ) + bh0g[1];
    float hn = SEL4(aN) + bh0g[2];
    float xr = bi0g[0], xz = bi0g[1], xn = bi0g[2];
    if (t < T_IN){
      const float* xp = x + (btb + bco)*(T_IN*10) + t*10;
      #pragma unroll
      for (int d = 0; d < 10; d++){
        float xv = xp[d];
        xr = fmaf(wi0[0][d], xv, xr);
        xz = fmaf(wi0[1][d], xv, xz);
        xn = fmaf(wi0[2][d], xv, xn);
      }
    }
    float r = sigf(xr + hr);
    float z = sigf(xz + hz);
    float n = tanhfast(xn + r*hn);
    float hnew1 = fmaf(z, HAf[hIdx] - n, n);
    h1nxt[(rowg << 8) + btb + bco] = hnew1;
    SWRITE(HB4);                       // h2[t-1] -> LDS
    __threadfence();
    __syncthreads();                                          // bar2 (drains h1 stores)
    if (tid == 0)
      __hip_atomic_fetch_add(cntA, 1u, __ATOMIC_RELEASE, __HIP_MEMORY_SCOPE_AGENT);

    // ---------------- layer 1 part A: whh1 . h2[t-1] ----------------
    float4 bR = {0,0,0,0}, bZ = {0,0,0,0}, bN = {0,0,0,0};
    GEMM3(HB4, 2, bR, bZ, bN);

    // THE wait: all h1[t] published
    if (tid == 0) WAIT(cntA, 32u*(unsigned)(t + 1));
    __syncthreads();                                          // bar3
    SLOAD(h1nxt); SWRITE(HA4);         // h1[t] -> HA (feeds GEMM1 now, GEMM0 next step)
    __syncthreads();                                          // bar4

    // ---------------- layer 1 part B: wih1 . h1[t] ----------------
    float4 xR = {0,0,0,0}, xZ = {0,0,0,0}, xN = {0,0,0,0};
    GEMM3(HA4, 1, xR, xZ, xN);
    xR = kred4(xR); xZ = kred4(xZ); xN = kred4(xN);
    bR = kred4(bR); bZ = kred4(bZ); bN = kred4(bN);
    float r1 = sigf(SEL4(xR) + bi1g[0] + SEL4(bR) + bh1g[0]);
    float z1 = sigf(SEL4(xZ) + bi1g[1] + SEL4(bZ) + bh1g[1]);
    float n1 = tanhfast(SEL4(xN) + bi1g[2] + r1*(SEL4(bN) + bh1g[2]));
    float h2new = fmaf(z1, HBf[hIdx] - n1, n1);
    h2nxt[(rowg << 8) + btb + bco] = h2new;
    if (t >= T_IN) PRJ[tid] = h2new * wp;
    __threadfence();
    __syncthreads();                                          // bar5 (drains h2 stores)
    if (tid == 0)
      __hip_atomic_fetch_add(cntB, 1u, __ATOMIC_RELEASE, __HIP_MEMORY_SCOPE_AGENT);

    // projection: 32 blocks share this bt -> each contributes its 8-row partial
    if (t >= T_IN && tid < 32){
      float s = 0.0f;
      #pragma unroll
      for (int hh = 0; hh < 8; hh++) s += PRJ[hh*32 + tid];
      atomicAdd(out + (btb + tid)*T_OUT + (t - T_IN), s);
    }
  }
}

extern "C" void kernel_launch(void* const* d_in, const int* in_sizes, int n_in,
                              void* d_out, int out_size, void* d_ws, size_t ws_size,
                              hipStream_t stream){
  const float* x     = (const float*)d_in[0];
  const float* wih0  = (const float*)d_in[1];
  const float* whh0  = (const float*)d_in[2];
  const float* bih0  = (const float*)d_in[3];
  const float* bhh0  = (const float*)d_in[4];
  const float* wih1  = (const float*)d_in[5];
  const float* whh1  = (const float*)d_in[6];
  const float* bih1  = (const float*)d_in[7];
  const float* bhh1  = (const float*)d_in[8];
  const float* wproj = (const float*)d_in[9];
  const float* bproj = (const float*)d_in[10];
  float* out = (float*)d_out;
  float* ws  = (float*)d_ws;

  hipLaunchKernelGGL(gru_init, dim3(1024), dim3(THREADS), 0, stream, ws, out, bproj);

  hipFuncSetAttribute(reinterpret_cast<const void*>(gru_persist),
                      hipFuncAttributeMaxDynamicSharedMemorySize, LDS_BYTES);

  void* args[] = {
    (void*)&x, (void*)&wih0, (void*)&whh0, (void*)&bih0, (void*)&bhh0,
    (void*)&wih1, (void*)&whh1, (void*)&bih1, (void*)&bhh1,
    (void*)&wproj, (void*)&out, (void*)&ws
  };
  hipLaunchCooperativeKernel(reinterpret_cast<void*>(gru_persist),
                             dim3(256), dim3(THREADS), args, LDS_BYTES, stream);
}

// Round 5
// 9368.034 us; speedup vs baseline: 4.0281x; 2.5192x over previous
//
#include <hip/hip_runtime.h>

#define THREADS 256
#define T_TOT 432
#define T_IN  144
#define T_OUT 288

// LDS float4 offsets
#define WSTRIDE 1552            // per-mat W stride (float4)
#define HA_OFF  4656            // 3*1552
#define HB_OFF  6704            // HA_OFF + 2048
#define PRJ_OFF 35008           // (HB_OFF+2048)*4 (float index)
#define LDS_BYTES 141056        // (PRJ_OFF+256)*4

// ws layout (floats): h1b0 [0,64K) h1b1 [64K,128K) h2b0 [128K,192K) h2b1 [192K,256K)
//   (global h layout: [k=256][b=256])
// counters: 512 uints at ws+262144; group bt: cntA = +bt*64, cntB = +bt*64+32

#define FMA4(a,h,s) { a.x=fmaf((h).x,(s),a.x); a.y=fmaf((h).y,(s),a.y); \
                      a.z=fmaf((h).z,(s),a.z); a.w=fmaf((h).w,(s),a.w); }

__device__ __forceinline__ float sigf(float x){ return 1.0f/(1.0f + __expf(-x)); }
__device__ __forceinline__ float tanhfast(float x){ return 1.0f - 2.0f/(__expf(2.0f*x)+1.0f); }

template<int CTRL>
__device__ __forceinline__ float4 dpp_add(float4 v){
  float4 r;
  r.x = v.x + __int_as_float(__builtin_amdgcn_update_dpp(0, __float_as_int(v.x), CTRL, 0xf, 0xf, true));
  r.y = v.y + __int_as_float(__builtin_amdgcn_update_dpp(0, __float_as_int(v.y), CTRL, 0xf, 0xf, true));
  r.z = v.z + __int_as_float(__builtin_amdgcn_update_dpp(0, __float_as_int(v.z), CTRL, 0xf, 0xf, true));
  r.w = v.w + __int_as_float(__builtin_amdgcn_update_dpp(0, __float_as_int(v.w), CTRL, 0xf, 0xf, true));
  return r;
}
__device__ __forceinline__ float4 kred4(float4 v){
  v = dpp_add<177>(v);   // quad_perm [1,0,3,2]  (xor 1)
  v = dpp_add<78>(v);    // quad_perm [2,3,0,1]  (xor 2)
  return v;
}

extern "C" __global__ void gru_init(float* __restrict__ ws, float* __restrict__ out,
                                    const float* __restrict__ b_proj){
  int i = blockIdx.x*THREADS + threadIdx.x;
  if (i < 262144) ws[i] = 0.0f;
  if (i < 512) ((unsigned*)(ws + 262144))[i] = 0u;
  if (i < 73728) out[i] = b_proj[0];
}

extern "C" __global__ void __launch_bounds__(THREADS, 1) gru_persist(
    const float* __restrict__ x,
    const float* __restrict__ wih0, const float* __restrict__ whh0,
    const float* __restrict__ bih0, const float* __restrict__ bhh0,
    const float* __restrict__ wih1, const float* __restrict__ whh1,
    const float* __restrict__ bih1, const float* __restrict__ bhh1,
    const float* __restrict__ wproj,
    float* __restrict__ out, float* __restrict__ ws)
{
  extern __shared__ float lds[];
  float4* WL4 = (float4*)lds;
  float4* HA4 = WL4 + HA_OFF;
  float4* HB4 = WL4 + HB_OFF;
  const float* HAf = (const float*)HA4;
  const float* HBf = (const float*)HB4;
  float* PRJ = lds + PRJ_OFF;

  const int tid = threadIdx.x;
  const int bt  = blockIdx.x & 7;     // batch tile — XCD-local group (round-robin dispatch)
  const int g   = blockIdx.x >> 3;    // hidden slice (8 rows)
  const int hi  = tid >> 5;           // 0..7
  const int bg  = (tid >> 2) & 7;     // 0..7 (4-batch group)
  const int ks  = tid & 3;            // K quarter
  const int bco = (bg << 2) | ks;     // owned batch col 0..31
  const int rowg = g*8 + hi;
  const int btb  = bt << 5;

  float* h1b0 = ws;
  float* h1b1 = ws + 65536;
  float* h2b0 = ws + 131072;
  float* h2b1 = ws + 196608;
  unsigned* cntA = ((unsigned*)(ws + 262144)) + (bt << 6);
  unsigned* cntB = cntA + 32;

  // ---- one-time: W slices -> skewed LDS [k4*24 + row + 4*(k4>>4)] (2-way reads = free) ----
  {
    const float* srcs[3] = {whh0, wih1, whh1};
    #pragma unroll
    for (int m = 0; m < 3; m++){
      const float* S = srcs[m];
      for (int i = 0; i < 6; i++){
        int idx = tid + (i << 8);
        int row = idx % 24;
        int k4  = idx / 24;
        int gate = row >> 3, hh = row & 7;
        float4 v = *(const float4*)(S + (gate*256 + g*8 + hh)*256 + (k4 << 2));
        WL4[m*WSTRIDE + k4*24 + row + ((k4 >> 4) << 2)] = v;
      }
    }
  }
  float wi0[3][10];
  float bi0g[3], bh0g[3], bi1g[3], bh1g[3];
  #pragma unroll
  for (int G = 0; G < 3; G++){
    #pragma unroll
    for (int d = 0; d < 10; d++) wi0[G][d] = wih0[(G*256 + rowg)*10 + d];
    bi0g[G] = bih0[G*256 + rowg];
    bh0g[G] = bhh0[G*256 + rowg];
    bi1g[G] = bih1[G*256 + rowg];
    bh1g[G] = bhh1[G*256 + rowg];
  }
  const float wp = wproj[rowg];
  // owner-readback index into H tile (conflict-free scalar)
  const int hIdx = (rowg << 5) + ((((bco >> 2) + ((rowg >> 6) << 1)) & 7) << 2) + (bco & 3);

  // H tile LDS layout: addr4(k,bq) = 8k + ((bq + 2*(k>>6)) & 7); conflict-free read+write
  float4 hreg[8];
  auto SLOAD = [&](const float* __restrict__ hg){
    #pragma unroll
    for (int i = 0; i < 8; i++){
      int idx = tid + (i << 8);
      hreg[i] = *(const float4*)(hg + ((idx >> 3) << 8) + btb + ((idx & 7) << 2));
    }
  };
  auto SWRITE = [&](float4* __restrict__ H4){
    #pragma unroll
    for (int i = 0; i < 8; i++){
      int idx = tid + (i << 8);
      int k = idx >> 3, bq = idx & 7;
      H4[(k << 3) + ((bq + ((k >> 6) << 1)) & 7)] = hreg[i];
    }
  };

  auto GEMM3 = [&](const float4* __restrict__ H4, int m,
                   float4& aR, float4& aZ, float4& aN){
    const float4* Wm = WL4 + m*WSTRIDE;
    const int wo = ks*388 + hi;
    const int hb = (ks << 9) + ((bg + (ks << 1)) & 7);
    #pragma unroll 4
    for (int j = 0; j < 16; j++){
      float4 wr = Wm[wo + j*24];
      float4 wz = Wm[wo + 8 + j*24];
      float4 wn = Wm[wo + 16 + j*24];
      float4 h0 = H4[hb + (j << 5)];
      float4 h1v = H4[hb + (j << 5) + 8];
      float4 h2v = H4[hb + (j << 5) + 16];
      float4 h3v = H4[hb + (j << 5) + 24];
      FMA4(aR,h0,wr.x) FMA4(aR,h1v,wr.y) FMA4(aR,h2v,wr.z) FMA4(aR,h3v,wr.w)
      FMA4(aZ,h0,wz.x) FMA4(aZ,h1v,wz.y) FMA4(aZ,h2v,wz.z) FMA4(aZ,h3v,wz.w)
      FMA4(aN,h0,wn.x) FMA4(aN,h1v,wn.y) FMA4(aN,h2v,wn.z) FMA4(aN,h3v,wn.w)
    }
  };

  auto SEL4 = [&](float4 v){
    return ks == 0 ? v.x : (ks == 1 ? v.y : (ks == 2 ? v.z : v.w));
  };
  auto WAIT = [&](unsigned* c, unsigned tgt){
    while (__hip_atomic_load(c, __ATOMIC_ACQUIRE, __HIP_MEMORY_SCOPE_AGENT) < tgt)
      __builtin_amdgcn_s_sleep(1);
  };

  __syncthreads();
  SLOAD(h1b1); SWRITE(HA4);            // h1[-1] = 0 tile (h1b1 zeroed)
  __syncthreads();

  for (int t = 0; t < T_TOT; t++){
    const float* h2prev = (t & 1) ? h2b0 : h2b1;
    float* h1nxt = (t & 1) ? h1b1 : h1b0;
    float* h2nxt = (t & 1) ? h2b1 : h2b0;

    // wait: h2[t-1] published (arriveB(t-1)); almost always instant
    if (tid == 0) WAIT(cntB, 32u*(unsigned)t);
    __syncthreads();                                          // bar1
    SLOAD(h2prev);                     // issue early; lands under GEMM0

    // ---------------- layer 0: whh0 . h1[t-1] (HA resident) ----------------
    float4 aR = {0,0,0,0}, aZ = {0,0,0,0}, aN = {0,0,0,0};
    GEMM3(HA4, 0, aR, aZ, aN);
    aR = kred4(aR); aZ = kred4(aZ); aN = kred4(aN);
    float hr = SEL4(aR) + bh0g[0];
    float hz = SEL4(aZ) + bh0g[1];
    float hn = SEL4(aN) + bh0g[2];
    float xr = bi0g[0], xz = bi0g[1], xn = bi0g[2];
    if (t < T_IN){
      const float* xp = x + (btb + bco)*(T_IN*10) + t*10;
      #pragma unroll
      for (int d = 0; d < 10; d++){
        float xv = xp[d];
        xr = fmaf(wi0[0][d], xv, xr);
        xz = fmaf(wi0[1][d], xv, xz);
        xn = fmaf(wi0[2][d], xv, xn);
      }
    }
    float r = sigf(xr + hr);
    float z = sigf(xz + hz);
    float n = tanhfast(xn + r*hn);
    float hnew1 = fmaf(z, HAf[hIdx] - n, n);
    h1nxt[(rowg << 8) + btb + bco] = hnew1;
    SWRITE(HB4);                       // h2[t-1] -> LDS
    __syncthreads();                                          // bar2 (drains h1 stores: vmcnt(0))
    if (tid == 0)
      __hip_atomic_fetch_add(cntA, 1u, __ATOMIC_RELEASE, __HIP_MEMORY_SCOPE_AGENT);

    // ---------------- layer 1 part A: whh1 . h2[t-1] ----------------
    float4 bR = {0,0,0,0}, bZ = {0,0,0,0}, bN = {0,0,0,0};
    GEMM3(HB4, 2, bR, bZ, bN);

    // THE wait: all h1[t] published
    if (tid == 0) WAIT(cntA, 32u*(unsigned)(t + 1));
    __syncthreads();                                          // bar3
    SLOAD(h1nxt); SWRITE(HA4);         // h1[t] -> HA (feeds GEMM1 now, GEMM0 next step)
    __syncthreads();                                          // bar4

    // ---------------- layer 1 part B: wih1 . h1[t] ----------------
    float4 xR = {0,0,0,0}, xZ = {0,0,0,0}, xN = {0,0,0,0};
    GEMM3(HA4, 1, xR, xZ, xN);
    xR = kred4(xR); xZ = kred4(xZ); xN = kred4(xN);
    bR = kred4(bR); bZ = kred4(bZ); bN = kred4(bN);
    float r1 = sigf(SEL4(xR) + bi1g[0] + SEL4(bR) + bh1g[0]);
    float z1 = sigf(SEL4(xZ) + bi1g[1] + SEL4(bZ) + bh1g[1]);
    float n1 = tanhfast(SEL4(xN) + bi1g[2] + r1*(SEL4(bN) + bh1g[2]));
    float h2new = fmaf(z1, HBf[hIdx] - n1, n1);
    h2nxt[(rowg << 8) + btb + bco] = h2new;
    if (t >= T_IN) PRJ[tid] = h2new * wp;
    __syncthreads();                                          // bar5 (drains h2 stores)
    if (tid == 0)
      __hip_atomic_fetch_add(cntB, 1u, __ATOMIC_RELEASE, __HIP_MEMORY_SCOPE_AGENT);

    // projection: 32 blocks share this bt -> each contributes its 8-row partial
    if (t >= T_IN && tid < 32){
      float s = 0.0f;
      #pragma unroll
      for (int hh = 0; hh < 8; hh++) s += PRJ[hh*32 + tid];
      atomicAdd(out + (btb + tid)*T_OUT + (t - T_IN), s);
    }
  }
}

extern "C" void kernel_launch(void* const* d_in, const int* in_sizes, int n_in,
                              void* d_out, int out_size, void* d_ws, size_t ws_size,
                              hipStream_t stream){
  const float* x     = (const float*)d_in[0];
  const float* wih0  = (const float*)d_in[1];
  const float* whh0  = (const float*)d_in[2];
  const float* bih0  = (const float*)d_in[3];
  const float* bhh0  = (const float*)d_in[4];
  const float* wih1  = (const float*)d_in[5];
  const float* whh1  = (const float*)d_in[6];
  const float* bih1  = (const float*)d_in[7];
  const float* bhh1  = (const float*)d_in[8];
  const float* wproj = (const float*)d_in[9];
  const float* bproj = (const float*)d_in[10];
  float* out = (float*)d_out;
  float* ws  = (float*)d_ws;

  hipLaunchKernelGGL(gru_init, dim3(1024), dim3(THREADS), 0, stream, ws, out, bproj);

  hipFuncSetAttribute(reinterpret_cast<const void*>(gru_persist),
                      hipFuncAttributeMaxDynamicSharedMemorySize, LDS_BYTES);

  void* args[] = {
    (void*)&x, (void*)&wih0, (void*)&whh0, (void*)&bih0, (void*)&bhh0,
    (void*)&wih1, (void*)&whh1, (void*)&bih1, (void*)&bhh1,
    (void*)&wproj, (void*)&out, (void*)&ws
  };
  hipLaunchCooperativeKernel(reinterpret_cast<void*>(gru_persist),
                             dim3(256), dim3(THREADS), args, LDS_BYTES, stream);
}

// Round 6
// 4110.911 us; speedup vs baseline: 9.1793x; 2.2788x over previous
//
#include <hip/hip_runtime.h>

#define THREADS 256
#define T_TOT 432
#define T_IN  144
#define T_OUT 288

// LDS float4 offsets
#define WSTRIDE 1552            // per-mat W stride (float4)
#define HA_OFF  4656            // 3*1552
#define HB_OFF  6704            // HA_OFF + 2048
#define PRJ_OFF 35008           // (HB_OFF+2048)*4 (float index)
#define LDS_BYTES 141056        // (PRJ_OFF+256)*4

// ws layout (floats): h1b0 [0,64K) h1b1 [64K,128K) h2b0 [128K,192K) h2b1 [192K,256K)
//   (global h layout: [k=256][b=256]) — exchanged via sc0/sc1 (MALL-coherent) ops only
// counters: 512 uints at ws+262144; group bt: cntA = +bt*64, cntB = +bt*64+32
//   accessed ONLY via relaxed agent atomics (RMW -> device coherence point; no wbl2/inv)

typedef float v4f __attribute__((ext_vector_type(4)));

#define FMA4(a,h,s) { a.x=fmaf((h).x,(s),a.x); a.y=fmaf((h).y,(s),a.y); \
                      a.z=fmaf((h).z,(s),a.z); a.w=fmaf((h).w,(s),a.w); }

// drain our async sc01 loads/stores; sched_barrier pins (rule #18 analog)
#define VMWAIT() do { asm volatile("s_waitcnt vmcnt(0)" ::: "memory"); \
                      __builtin_amdgcn_sched_barrier(0); } while(0)

__device__ __forceinline__ float sigf(float x){ return 1.0f/(1.0f + __expf(-x)); }
__device__ __forceinline__ float tanhfast(float x){ return 1.0f - 2.0f/(__expf(2.0f*x)+1.0f); }

template<int CTRL>
__device__ __forceinline__ float4 dpp_add(float4 v){
  float4 r;
  r.x = v.x + __int_as_float(__builtin_amdgcn_update_dpp(0, __float_as_int(v.x), CTRL, 0xf, 0xf, true));
  r.y = v.y + __int_as_float(__builtin_amdgcn_update_dpp(0, __float_as_int(v.y), CTRL, 0xf, 0xf, true));
  r.z = v.z + __int_as_float(__builtin_amdgcn_update_dpp(0, __float_as_int(v.z), CTRL, 0xf, 0xf, true));
  r.w = v.w + __int_as_float(__builtin_amdgcn_update_dpp(0, __float_as_int(v.w), CTRL, 0xf, 0xf, true));
  return r;
}
__device__ __forceinline__ float4 kred4(float4 v){
  v = dpp_add<177>(v);   // quad_perm [1,0,3,2]  (xor 1)
  v = dpp_add<78>(v);    // quad_perm [2,3,0,1]  (xor 2)
  return v;
}

extern "C" __global__ void gru_init(float* __restrict__ ws, float* __restrict__ out,
                                    const float* __restrict__ b_proj){
  int i = blockIdx.x*THREADS + threadIdx.x;
  if (i < 262144) ws[i] = 0.0f;
  if (i < 512) ((unsigned*)(ws + 262144))[i] = 0u;
  if (i < 73728) out[i] = b_proj[0];
}

extern "C" __global__ void __launch_bounds__(THREADS, 1) gru_persist(
    const float* __restrict__ x,
    const float* __restrict__ wih0, const float* __restrict__ whh0,
    const float* __restrict__ bih0, const float* __restrict__ bhh0,
    const float* __restrict__ wih1, const float* __restrict__ whh1,
    const float* __restrict__ bih1, const float* __restrict__ bhh1,
    const float* __restrict__ wproj,
    float* __restrict__ out, float* __restrict__ ws)
{
  extern __shared__ float lds[];
  float4* WL4 = (float4*)lds;
  float4* HA4 = WL4 + HA_OFF;
  float4* HB4 = WL4 + HB_OFF;
  const float* HAf = (const float*)HA4;
  const float* HBf = (const float*)HB4;
  float* PRJ = lds + PRJ_OFF;

  const int tid = threadIdx.x;
  const int bt  = blockIdx.x & 7;     // batch tile
  const int g   = blockIdx.x >> 3;    // hidden slice (8 rows)
  const int hi  = tid >> 5;           // 0..7
  const int bg  = (tid >> 2) & 7;     // 0..7 (4-batch group)
  const int ks  = tid & 3;            // K quarter
  const int bco = (bg << 2) | ks;     // owned batch col 0..31
  const int rowg = g*8 + hi;
  const int btb  = bt << 5;

  float* h1b0 = ws;
  float* h1b1 = ws + 65536;
  float* h2b0 = ws + 131072;
  float* h2b1 = ws + 196608;
  unsigned* cntA = ((unsigned*)(ws + 262144)) + (bt << 6);
  unsigned* cntB = cntA + 32;

  // ---- one-time: W slices -> skewed LDS [k4*24 + row + 4*(k4>>4)] ----
  {
    const float* srcs[3] = {whh0, wih1, whh1};
    #pragma unroll
    for (int m = 0; m < 3; m++){
      const float* S = srcs[m];
      for (int i = 0; i < 6; i++){
        int idx = tid + (i << 8);
        int row = idx % 24;
        int k4  = idx / 24;
        int gate = row >> 3, hh = row & 7;
        float4 v = *(const float4*)(S + (gate*256 + g*8 + hh)*256 + (k4 << 2));
        WL4[m*WSTRIDE + k4*24 + row + ((k4 >> 4) << 2)] = v;
      }
    }
  }
  float wi0[3][10];
  float bi0g[3], bh0g[3], bi1g[3], bh1g[3];
  #pragma unroll
  for (int G = 0; G < 3; G++){
    #pragma unroll
    for (int d = 0; d < 10; d++) wi0[G][d] = wih0[(G*256 + rowg)*10 + d];
    bi0g[G] = bih0[G*256 + rowg];
    bh0g[G] = bhh0[G*256 + rowg];
    bi1g[G] = bih1[G*256 + rowg];
    bh1g[G] = bhh1[G*256 + rowg];
  }
  const float wp = wproj[rowg];
  const int hIdx = (rowg << 5) + ((((bco >> 2) + ((rowg >> 6) << 1)) & 7) << 2) + (bco & 3);

  // H tile LDS layout: addr4(k,bq) = 8k + ((bq + 2*(k>>6)) & 7); conflict-free
  v4f hreg[8];
  // MALL-coherent tile load (sc0 sc1 -> bypass L1+L2); results valid after VMWAIT()
  auto SLOADC = [&](const float* __restrict__ hg){
    #pragma unroll
    for (int i = 0; i < 8; i++){
      int idx = tid + (i << 8);
      const float* p = hg + ((idx >> 3) << 8) + btb + ((idx & 7) << 2);
      asm volatile("global_load_dwordx4 %0, %1, off sc0 sc1"
                   : "=v"(hreg[i]) : "v"(p) : "memory");
    }
  };
  auto SWRITE = [&](float4* __restrict__ H4){
    #pragma unroll
    for (int i = 0; i < 8; i++){
      int idx = tid + (i << 8);
      int k = idx >> 3, bq = idx & 7;
      *(v4f*)&H4[(k << 3) + ((bq + ((k >> 6) << 1)) & 7)] = hreg[i];
    }
  };
  auto HSTORE = [&](float* p, float v){
    asm volatile("global_store_dword %0, %1, off sc0 sc1" :: "v"(p), "v"(v) : "memory");
  };

  auto GEMM3 = [&](const float4* __restrict__ H4, int m,
                   float4& aR, float4& aZ, float4& aN){
    const float4* Wm = WL4 + m*WSTRIDE;
    const int wo = ks*388 + hi;
    const int hb = (ks << 9) + ((bg + (ks << 1)) & 7);
    #pragma unroll 4
    for (int j = 0; j < 16; j++){
      float4 wr = Wm[wo + j*24];
      float4 wz = Wm[wo + 8 + j*24];
      float4 wn = Wm[wo + 16 + j*24];
      float4 h0 = H4[hb + (j << 5)];
      float4 h1v = H4[hb + (j << 5) + 8];
      float4 h2v = H4[hb + (j << 5) + 16];
      float4 h3v = H4[hb + (j << 5) + 24];
      FMA4(aR,h0,wr.x) FMA4(aR,h1v,wr.y) FMA4(aR,h2v,wr.z) FMA4(aR,h3v,wr.w)
      FMA4(aZ,h0,wz.x) FMA4(aZ,h1v,wz.y) FMA4(aZ,h2v,wz.z) FMA4(aZ,h3v,wz.w)
      FMA4(aN,h0,wn.x) FMA4(aN,h1v,wn.y) FMA4(aN,h2v,wn.z) FMA4(aN,h3v,wn.w)
    }
  };

  auto SEL4 = [&](float4 v){
    return ks == 0 ? v.x : (ks == 1 ? v.y : (ks == 2 ? v.z : v.w));
  };
  // relaxed RMW poll: coherent at device point, NO buffer_inv/wbl2 side effects
  auto WAIT = [&](unsigned* c, unsigned tgt){
    while (__hip_atomic_fetch_add(c, 0u, __ATOMIC_RELAXED, __HIP_MEMORY_SCOPE_AGENT) < tgt)
      __builtin_amdgcn_s_sleep(4);
  };
  auto ARRIVE = [&](unsigned* c){
    __hip_atomic_fetch_add(c, 1u, __ATOMIC_RELAXED, __HIP_MEMORY_SCOPE_AGENT);
  };

  __syncthreads();
  SLOADC(h1b1);                        // h1[-1] = 0 tile (zeros visible via kernel-boundary release)
  VMWAIT();
  SWRITE(HA4);
  __syncthreads();

  for (int t = 0; t < T_TOT; t++){
    const float* h2prev = (t & 1) ? h2b0 : h2b1;
    float* h1nxt = (t & 1) ? h1b1 : h1b0;
    float* h2nxt = (t & 1) ? h2b1 : h2b0;

    // wait: h2[t-1] published; almost always instant (arrived last step)
    if (tid == 0) WAIT(cntB, 32u*(unsigned)t);
    __syncthreads();                                          // bar1
    SLOADC(h2prev);                    // MALL read lands under GEMM0

    // ---------------- layer 0: whh0 . h1[t-1] (HA resident) ----------------
    float4 aR = {0,0,0,0}, aZ = {0,0,0,0}, aN = {0,0,0,0};
    GEMM3(HA4, 0, aR, aZ, aN);
    aR = kred4(aR); aZ = kred4(aZ); aN = kred4(aN);
    float hr = SEL4(aR) + bh0g[0];
    float hz = SEL4(aZ) + bh0g[1];
    float hn = SEL4(aN) + bh0g[2];
    float xr = bi0g[0], xz = bi0g[1], xn = bi0g[2];
    if (t < T_IN){
      const float* xp = x + (btb + bco)*(T_IN*10) + t*10;
      #pragma unroll
      for (int d = 0; d < 10; d++){
        float xv = xp[d];
        xr = fmaf(wi0[0][d], xv, xr);
        xz = fmaf(wi0[1][d], xv, xz);
        xn = fmaf(wi0[2][d], xv, xn);
      }
    }
    float r = sigf(xr + hr);
    float z = sigf(xz + hz);
    float n = tanhfast(xn + r*hn);
    float hnew1 = fmaf(z, HAf[hIdx] - n, n);
    HSTORE(h1nxt + (rowg << 8) + btb + bco, hnew1);
    VMWAIT();                          // drain h2prev loads + h1 store (acked at MALL)
    SWRITE(HB4);                       // h2[t-1] -> LDS
    __syncthreads();                                          // bar2
    if (tid == 0) ARRIVE(cntA);

    // wait h1[t] BEFORE GEMM2 so the MALL read overlaps GEMM2
    if (tid == 0) WAIT(cntA, 32u*(unsigned)(t + 1));
    __syncthreads();                                          // bar3
    SLOADC(h1nxt);                     // lands under GEMM2

    // ---------------- layer 1 part A: whh1 . h2[t-1] ----------------
    float4 bR = {0,0,0,0}, bZ = {0,0,0,0}, bN = {0,0,0,0};
    GEMM3(HB4, 2, bR, bZ, bN);
    VMWAIT();                          // h1[t] tile arrived
    SWRITE(HA4);                       // h1[t] -> HA (feeds GEMM1 now, GEMM0 next step)
    __syncthreads();                                          // bar4

    // ---------------- layer 1 part B: wih1 . h1[t] ----------------
    float4 xR = {0,0,0,0}, xZ = {0,0,0,0}, xN = {0,0,0,0};
    GEMM3(HA4, 1, xR, xZ, xN);
    xR = kred4(xR); xZ = kred4(xZ); xN = kred4(xN);
    bR = kred4(bR); bZ = kred4(bZ); bN = kred4(bN);
    float r1 = sigf(SEL4(xR) + bi1g[0] + SEL4(bR) + bh1g[0]);
    float z1 = sigf(SEL4(xZ) + bi1g[1] + SEL4(bZ) + bh1g[1]);
    float n1 = tanhfast(SEL4(xN) + bi1g[2] + r1*(SEL4(bN) + bh1g[2]));
    float h2new = fmaf(z1, HBf[hIdx] - n1, n1);
    HSTORE(h2nxt + (rowg << 8) + btb + bco, h2new);
    if (t >= T_IN) PRJ[tid] = h2new * wp;
    VMWAIT();                          // h2 store acked at MALL
    __syncthreads();                                          // bar5
    if (tid == 0) ARRIVE(cntB);

    // projection: 32 blocks share this bt -> each contributes its 8-row partial
    if (t >= T_IN && tid < 32){
      float s = 0.0f;
      #pragma unroll
      for (int hh = 0; hh < 8; hh++) s += PRJ[hh*32 + tid];
      atomicAdd(out + (btb + tid)*T_OUT + (t - T_IN), s);
    }
  }
}

extern "C" void kernel_launch(void* const* d_in, const int* in_sizes, int n_in,
                              void* d_out, int out_size, void* d_ws, size_t ws_size,
                              hipStream_t stream){
  const float* x     = (const float*)d_in[0];
  const float* wih0  = (const float*)d_in[1];
  const float* whh0  = (const float*)d_in[2];
  const float* bih0  = (const float*)d_in[3];
  const float* bhh0  = (const float*)d_in[4];
  const float* wih1  = (const float*)d_in[5];
  const float* whh1  = (const float*)d_in[6];
  const float* bih1  = (const float*)d_in[7];
  const float* bhh1  = (const float*)d_in[8];
  const float* wproj = (const float*)d_in[9];
  const float* bproj = (const float*)d_in[10];
  float* out = (float*)d_out;
  float* ws  = (float*)d_ws;

  hipLaunchKernelGGL(gru_init, dim3(1024), dim3(THREADS), 0, stream, ws, out, bproj);

  hipFuncSetAttribute(reinterpret_cast<const void*>(gru_persist),
                      hipFuncAttributeMaxDynamicSharedMemorySize, LDS_BYTES);

  void* args[] = {
    (void*)&x, (void*)&wih0, (void*)&whh0, (void*)&bih0, (void*)&bhh0,
    (void*)&wih1, (void*)&whh1, (void*)&bih1, (void*)&bhh1,
    (void*)&wproj, (void*)&out, (void*)&ws
  };
  hipLaunchCooperativeKernel(reinterpret_cast<void*>(gru_persist),
                             dim3(256), dim3(THREADS), args, LDS_BYTES, stream);
}